// Round 5
// baseline (1481.599 us; speedup 1.0000x reference)
//
#include <hip/hip_runtime.h>

typedef _Float16 f16;
typedef _Float16 f16x4 __attribute__((ext_vector_type(4)));
typedef _Float16 f16x8 __attribute__((ext_vector_type(8)));
typedef float f32x4 __attribute__((ext_vector_type(4)));

#define NB   8
#define HW   5476
#define NL   32
#define DIM  1024
#define LIN  768
#define MTOT (NB * HW)            // 43808
#define MT256 ((MTOT + 255) / 256)  // 172 row-tiles of 256
#define CSPLIT 128                // colstats row-splits per batch

// ---------------------------------------------------------------- utilities

__device__ __forceinline__ void g2l16(const void* g, void* l) {
#if __has_builtin(__builtin_amdgcn_global_load_lds)
  __builtin_amdgcn_global_load_lds(
      (const __attribute__((address_space(1))) void*)g,
      (__attribute__((address_space(3))) void*)l, 16, 0, 0);
#else
  const int lane = threadIdx.x & 63;
  *(uint4*)((char*)l + lane * 16) = *(const uint4*)g;
#endif
}

__device__ __forceinline__ float gelu_f(float x) {
  return 0.5f * x * (1.0f + erff(x * 0.70710678118654752f));
}

#define WAITV(N) asm volatile("s_waitcnt vmcnt(" #N ")" ::: "memory")
__device__ __forceinline__ void barrier_nf() {
  asm volatile("s_barrier" ::: "memory");  // raw barrier, no vmcnt drain
}

// ---------------------------------------------------------------- big GEMM
// C[M,N] = A[M,K] * W[N,K]^T (+bias, epilogue). K = N = 1024.
// 8-phase (T3+T4) 256x256 template: BK=64 (16 K-tiles), 8 waves (2M x 4N),
// two 64KB K-tile LDS buffers (128 KiB). Per K-tile, 4 phases of
// {ds_read quadrant frags || stage one half-tile of tile t+1 -> barrier ->
// 16 MFMA (setprio) -> barrier}. Staging targets buf c^1 while reads hit
// buf c -> race-free by construction; barriers are schedule-shaping only.
// vmcnt(0) once per K-tile, >=1 phase after last prefetch issue.
// T2 (BK=64 form): LDS 16B-chunk' = chunk ^ (row&7); involution applied on
// the pre-swizzled global SOURCE of global_load_lds (linear dest) and on
// the ds_read address. Each ds_read_b128 spreads 8 lanes/chunk over all 8
// chunk-columns (distinct rows) -> b128 8-beat floor, conflict-free.
// T1: bijective XCD swizzle, mt FASTEST: each XCD pins one 512KB W-panel
// in its L2 and streams A (L3-served after first touch).
// EPI: 0 = gelu->f16, 1 = plain->f16, 2 = plain->f32, 3 = gelu->f32
// EPI2 >= 0: dual-output mode; blocks with nt >= 4 use W2/bias2/out2.
template <int EPI, int EPI2>
__global__ __launch_bounds__(512, 2) void gemm256(
    const f16* __restrict__ A, const f16* __restrict__ W,
    const float* __restrict__ bias, void* __restrict__ out,
    const f16* __restrict__ W2, const float* __restrict__ bias2,
    void* __restrict__ out2, int M) {
  constexpr int K = 1024, N = 1024;
  constexpr int KT = K / 64;               // 16 K-tiles
  constexpr int NT = (EPI2 >= 0) ? 8 : 4;  // 256-col tiles (dual: 4 + 4)
  constexpr int NWG = NT * MT256;          // 1376 / 688, both % 8 == 0
  constexpr int CHUNK = NWG / 8;
  __shared__ f16 lds[2][2][256 * 64];  // [buf][A=0/B=1][row*64 ^swz]

  // T1: xcd = blockIdx.x % 8 (hardware round-robin). mt fast, nt slow.
  const int L = blockIdx.x;
  const int w = (L & 7) * CHUNK + (L >> 3);
  const int mt = w % MT256;
  int nt = w / MT256;
  const f16* Wp = W;
  const float* bp = bias;
  void* op = out;
  bool second = false;
  if constexpr (EPI2 >= 0) {
    if (nt >= 4) {
      nt -= 4;
      Wp = W2;
      bp = bias2;
      op = out2;
      second = true;
    }
  }

  const int tid = threadIdx.x;
  const int wave = tid >> 6, lane = tid & 63;
  const int m0 = mt * 256, n0 = nt * 256;
  const int wm = (wave >> 2) * 128;  // 2 waves in M
  const int wn = (wave & 3) * 64;    // 4 waves in N
  const int fr = lane & 15, fq = lane >> 4;

  f32x4 acc[8][4];
#pragma unroll
  for (int i = 0; i < 8; ++i)
#pragma unroll
    for (int j = 0; j < 4; ++j) acc[i][j] = (f32x4){0.f, 0.f, 0.f, 0.f};

  // Stage-side source pre-swizzle. Per gload instruction a wave fills 8
  // rows x 128B linearly; lane -> LDS (row lane>>3, chunk lane&7); source
  // chunk = (lane&7) ^ ((lane>>3)&7)  (row groups are 8-aligned).
  const int sub8 = lane >> 3;
  const int srcc = ((lane & 7) ^ sub8) * 8;  // f16 element offset in row

  // stage one half-tile (128 rows x 64 cols) of A or B: 2 gloads/thread.
  auto stageA = [&](int t, int half) {
    const int buf = t & 1, k0 = t * 64;
#pragma unroll
    for (int k = 0; k < 2; ++k) {
      const int rl = (wave * 2 + k) * 8 + sub8;
      int gm = m0 + half * 128 + rl;
      if (gm > M - 1) gm = M - 1;
      g2l16(A + (size_t)gm * K + k0 + srcc,
            &lds[buf][0][half * 8192 + (wave * 2 + k) * 512]);
    }
  };
  auto stageB = [&](int t, int half) {
    const int buf = t & 1, k0 = t * 64;
#pragma unroll
    for (int k = 0; k < 2; ++k) {
      const int rl = (wave * 2 + k) * 8 + sub8;
      const int gn = n0 + half * 128 + rl;
      g2l16(Wp + (size_t)gn * K + k0 + srcc,
            &lds[buf][1][half * 8192 + (wave * 2 + k) * 512]);
    }
  };

  f16x8 bf[4];
  auto readB = [&](int t, int s) {
    const f16* Bb = &lds[t & 1][1][0];
#pragma unroll
    for (int j = 0; j < 4; ++j) {
      const int row = wn + j * 16 + fr;
      bf[j] = *(const f16x8*)&Bb[row * 64 + (((s * 4 + fq) ^ (row & 7)) * 8)];
    }
  };
  auto readA = [&](int t, int q, int s, f16x8* af) {
    const f16* Ab = &lds[t & 1][0][0];
#pragma unroll
    for (int i = 0; i < 4; ++i) {
      const int row = wm + (q * 4 + i) * 16 + fr;
      af[i] = *(const f16x8*)&Ab[row * 64 + (((s * 4 + fq) ^ (row & 7)) * 8)];
    }
  };
  auto mfma16 = [&](int q, const f16x8* af) {
    __builtin_amdgcn_s_setprio(1);
#pragma unroll
    for (int i = 0; i < 4; ++i)
#pragma unroll
      for (int j = 0; j < 4; ++j)
        acc[q * 4 + i][j] = __builtin_amdgcn_mfma_f32_16x16x32_f16(
            af[i], bf[j], acc[q * 4 + i][j], 0, 0, 0);
    __builtin_amdgcn_s_setprio(0);
  };

  // prologue: tile 0 fully staged
  stageA(0, 0); stageB(0, 0); stageA(0, 1); stageB(0, 1);
  WAITV(0);
  barrier_nf();

  for (int t = 0; t < KT; ++t) {
    f16x8 af[4];
    const bool pf = (t + 1 < KT);
    // phase 1: quad 0, ksub 0  (+ prefetch A0,B0 of t+1)
    readB(t, 0);
    readA(t, 0, 0, af);
    if (pf) { stageA(t + 1, 0); stageB(t + 1, 0); }
    barrier_nf();
    mfma16(0, af);
    barrier_nf();
    // phase 2: quad 1, ksub 0  (+ prefetch A1)
    readA(t, 1, 0, af);
    if (pf) stageA(t + 1, 1);
    barrier_nf();
    mfma16(1, af);
    barrier_nf();
    // phase 3: quad 0, ksub 1  (+ prefetch B1)
    readB(t, 1);
    readA(t, 0, 1, af);
    if (pf) stageB(t + 1, 1);
    barrier_nf();
    mfma16(0, af);
    barrier_nf();
    // phase 4: quad 1, ksub 1  (+ counted drain: t+1 fully landed)
    readA(t, 1, 1, af);
    WAITV(0);
    barrier_nf();
    mfma16(1, af);
    barrier_nf();
  }

  // Epilogue. C/D layout: col = lane&15, row = (lane>>4)*4 + reg.
  const bool do_gelu = second ? (EPI2 == 0 || EPI2 == 3) : (EPI == 0 || EPI == 3);
  const bool to_f16 = second ? (EPI2 <= 1) : (EPI <= 1);
  const int row0 = m0 + wm + fq * 4;
  const int col0 = n0 + wn + fr;
#pragma unroll
  for (int j = 0; j < 4; ++j) {
    const int col = col0 + j * 16;
    const float bv = bp[col];
#pragma unroll
    for (int i = 0; i < 8; ++i) {
#pragma unroll
      for (int r = 0; r < 4; ++r) {
        const int row = row0 + i * 16 + r;
        if (row < M) {
          float v = acc[i][j][r] + bv;
          if (do_gelu) v = gelu_f(v);
          if (to_f16)
            ((f16*)op)[(size_t)row * N + col] = (f16)v;
          else
            ((float*)op)[(size_t)row * N + col] = v;
        }
      }
    }
  }
}

// ---------------------------------------------------------------- fp32 -> fp16
__global__ void cvt_f32_f16(const float* __restrict__ in, f16* __restrict__ out,
                            int nchunks) {
  const int i = blockIdx.x * 256 + threadIdx.x;
  if (i >= nchunks) return;
  const float4* p = (const float4*)in + (size_t)i * 2;
  const float4 a = p[0], b = p[1];
  f16x8 o = {(f16)a.x, (f16)a.y, (f16)a.z, (f16)a.w,
             (f16)b.x, (f16)b.y, (f16)b.z, (f16)b.w};
  *((f16x8*)out + i) = o;
}

// ---------------------------------------------------------------- column stats
template <typename T>
__global__ __launch_bounds__(256) void colstats_partial(
    const T* __restrict__ X, float* __restrict__ psum,
    float* __restrict__ psq) {
  const int b = blockIdx.y;
  const int sp = blockIdx.x;
  const int c = threadIdx.x * 4;  // 4 columns per thread
  constexpr int CHUNK = (HW + CSPLIT - 1) / CSPLIT;  // 43
  const int r0 = sp * CHUNK;
  const int r1 = (r0 + CHUNK < HW) ? r0 + CHUNK : HW;

  float s0 = 0.f, s1 = 0.f, s2 = 0.f, s3 = 0.f;
  float q0 = 0.f, q1 = 0.f, q2 = 0.f, q3 = 0.f;
  const T* base = X + ((size_t)b * HW + r0) * DIM + c;
  for (int r = r0; r < r1; ++r) {
    float v0, v1, v2, v3;
    if constexpr (sizeof(T) == 2) {
      const f16x4 v = *(const f16x4*)base;
      v0 = (float)v[0]; v1 = (float)v[1]; v2 = (float)v[2]; v3 = (float)v[3];
    } else {
      const float4 v = *(const float4*)base;
      v0 = v.x; v1 = v.y; v2 = v.z; v3 = v.w;
    }
    s0 += v0; s1 += v1; s2 += v2; s3 += v3;
    q0 += v0 * v0; q1 += v1 * v1; q2 += v2 * v2; q3 += v3 * v3;
    base += DIM;
  }
  const size_t o = ((size_t)sp * NB + b) * DIM + c;
  *(float4*)&psum[o] = make_float4(s0, s1, s2, s3);
  *(float4*)&psq[o] = make_float4(q0, q1, q2, q3);
}

__global__ __launch_bounds__(256) void colstats_final(
    const float* __restrict__ psum, const float* __restrict__ psq,
    float* __restrict__ mean, float* __restrict__ rinv) {
  const int i = blockIdx.x * 256 + threadIdx.x;  // over NB*DIM = 8192
  float s = 0.f, q = 0.f;
  for (int sp = 0; sp < CSPLIT; ++sp) {
    s += psum[(size_t)sp * NB * DIM + i];
    q += psq[(size_t)sp * NB * DIM + i];
  }
  const float m = s * (1.0f / HW);
  const float var = q * (1.0f / HW) - m * m;
  mean[i] = m;
  rinv[i] = rsqrtf(var + 1e-5f);
}

// ---------------------------------------------------------------- k/v small GEMM
__global__ __launch_bounds__(256) void kv_gemm(
    const float* __restrict__ l, const float* __restrict__ lmask,
    const float* __restrict__ wk, const float* __restrict__ bk,
    const float* __restrict__ wv, const float* __restrict__ bv,
    float* __restrict__ Kout, float* __restrict__ Vout) {
  const int b = blockIdx.z;
  const int o0 = blockIdx.x * 64;
  const float* w = blockIdx.y ? wv : wk;
  const float* bb = blockIdx.y ? bv : bk;
  float* out = blockIdx.y ? Vout : Kout;

  __shared__ float wl[64 * 129];
  __shared__ float ll[32 * 129];
  const int tid = threadIdx.x;
  const int o = tid & 63, ng = tid >> 6;  // each thread: 1 o x 8 n
  float acc[8];
#pragma unroll
  for (int j = 0; j < 8; ++j) acc[j] = 0.f;

  for (int kc = 0; kc < LIN; kc += 128) {
    for (int e = tid; e < 64 * 128; e += 256)
      wl[(e >> 7) * 129 + (e & 127)] =
          w[(size_t)(o0 + (e >> 7)) * LIN + kc + (e & 127)];
    for (int e = tid; e < 32 * 128; e += 256)
      ll[(e >> 7) * 129 + (e & 127)] =
          l[(size_t)b * NL * LIN + (size_t)(e >> 7) * LIN + kc + (e & 127)];
    __syncthreads();
    for (int k = 0; k < 128; ++k) {
      const float wv_ = wl[o * 129 + k];
#pragma unroll
      for (int j = 0; j < 8; ++j) acc[j] += wv_ * ll[(ng * 8 + j) * 129 + k];
    }
    __syncthreads();
  }
  const float bval = bb[o0 + o];
#pragma unroll
  for (int j = 0; j < 8; ++j) {
    const int n = ng * 8 + j;
    out[((size_t)b * DIM + o0 + o) * NL + n] =
        (acc[j] + bval) * lmask[b * NL + n];
  }
}

// ---------------------------------------------------------------- attention
__global__ __launch_bounds__(256) void attn_kernel(
    const f16* __restrict__ Q, const float* __restrict__ qmean,
    const float* __restrict__ qrinv, const float* __restrict__ Kk,
    const float* __restrict__ Vv, const float* __restrict__ lmask,
    float* __restrict__ Out) {
  const int b = blockIdx.z, h = blockIdx.y;
  __shared__ float ks[128 * NL], vs[128 * NL], qm[128], qr[128], bs[NL];
  const int tid = threadIdx.x;
  const float* kbase = Kk + ((size_t)b * DIM + h * 128) * NL;
  const float* vbase = Vv + ((size_t)b * DIM + h * 128) * NL;
  for (int i = tid; i < 128 * NL; i += 256) {
    ks[i] = kbase[i];
    vs[i] = vbase[i];
  }
  if (tid < 128) {
    qm[tid] = qmean[b * DIM + h * 128 + tid];
    qr[tid] = qrinv[b * DIM + h * 128 + tid];
  }
  if (tid < NL) bs[tid] = (lmask[b * NL + tid] - 1.0f) * 10000.0f;
  __syncthreads();

  const int mloc = blockIdx.x * 256 + tid;
  if (mloc >= HW) return;
  const size_t m = (size_t)b * HW + mloc;
  const f16* qrow = Q + m * DIM + h * 128;

  float sc[32];
#pragma unroll
  for (int n = 0; n < 32; ++n) sc[n] = 0.f;

  for (int d8 = 0; d8 < 16; ++d8) {
    const f16x8 qv = *(const f16x8*)(qrow + d8 * 8);
#pragma unroll
    for (int j = 0; j < 8; ++j) {
      const int d = d8 * 8 + j;
      const float qd = ((float)qv[j] - qm[d]) * qr[d];
      const float4* kr = (const float4*)&ks[d * 32];
#pragma unroll
      for (int n4 = 0; n4 < 8; ++n4) {
        const float4 kk = kr[n4];
        sc[n4 * 4 + 0] += qd * kk.x;
        sc[n4 * 4 + 1] += qd * kk.y;
        sc[n4 * 4 + 2] += qd * kk.z;
        sc[n4 * 4 + 3] += qd * kk.w;
      }
    }
  }
  float mx = -1e30f;
#pragma unroll
  for (int n = 0; n < 32; ++n) {
    sc[n] = sc[n] * 0.03125f + bs[n];  // * KC^-0.5 then masked bias
    mx = fmaxf(mx, sc[n]);
  }
  float sum = 0.f;
#pragma unroll
  for (int n = 0; n < 32; ++n) {
    sc[n] = __expf(sc[n] - mx);
    sum += sc[n];
  }
  const float rs = 1.0f / sum;

  float* orow = Out + m * DIM + h * 128;
  for (int dv8 = 0; dv8 < 16; ++dv8) {
    float ov[8];
#pragma unroll
    for (int j = 0; j < 8; ++j) {
      const float4* vr = (const float4*)&vs[(dv8 * 8 + j) * 32];
      float a = 0.f;
#pragma unroll
      for (int n4 = 0; n4 < 8; ++n4) {
        const float4 vv = vr[n4];
        a += sc[n4 * 4 + 0] * vv.x + sc[n4 * 4 + 1] * vv.y +
             sc[n4 * 4 + 2] * vv.z + sc[n4 * 4 + 3] * vv.w;
      }
      ov[j] = a * rs;
    }
    float4* op = (float4*)(orow + dv8 * 8);
    op[0] = make_float4(ov[0], ov[1], ov[2], ov[3]);
    op[1] = make_float4(ov[4], ov[5], ov[6], ov[7]);
  }
}

// ---------------------------------------------------------------- center (attn - colmean) -> f16
__global__ void center_kernel(const float* __restrict__ X,
                              const float* __restrict__ mean,
                              f16* __restrict__ out, int nchunks) {
  const int i = blockIdx.x * 256 + threadIdx.x;
  if (i >= nchunks) return;
  const size_t e = (size_t)i * 8;
  const int mrow = (int)(e >> 10);
  const int o = (int)(e & 1023);
  const int b = mrow / HW;
  const float4* p = (const float4*)(X + e);
  const float4 a = p[0], c = p[1];
  const float* mn = mean + b * DIM + o;
  f16x8 r = {(f16)(a.x - mn[0]), (f16)(a.y - mn[1]), (f16)(a.z - mn[2]),
             (f16)(a.w - mn[3]), (f16)(c.x - mn[4]), (f16)(c.y - mn[5]),
             (f16)(c.z - mn[6]), (f16)(c.w - mn[7])};
  *((f16x8*)out + i) = r;
}

// ---------------------------------------------------------------- fuse: mm = vis * inorm(lang_pre)
__global__ void fuse_kernel(const f16* __restrict__ vis,
                            const float* __restrict__ lang,
                            const float* __restrict__ mean,
                            const float* __restrict__ rinv,
                            f16* __restrict__ out, int nchunks) {
  const int i = blockIdx.x * 256 + threadIdx.x;
  if (i >= nchunks) return;
  const size_t e = (size_t)i * 8;
  const int mrow = (int)(e >> 10);
  const int o = (int)(e & 1023);
  const int b = mrow / HW;
  const f16x8 v = *((const f16x8*)vis + i);
  const float4* p = (const float4*)(lang + e);
  const float4 a = p[0], c = p[1];
  const float lv[8] = {a.x, a.y, a.z, a.w, c.x, c.y, c.z, c.w};
  const float* mn = mean + b * DIM + o;
  const float* ri = rinv + b * DIM + o;
  f16x8 r;
#pragma unroll
  for (int j = 0; j < 8; ++j)
    r[j] = (f16)((float)v[j] * ((lv[j] - mn[j]) * ri[j]));
  *((f16x8*)out + i) = r;
}

// ---------------------------------------------------------------- launch
extern "C" void kernel_launch(void* const* d_in, const int* in_sizes, int n_in,
                              void* d_out, int out_size, void* d_ws,
                              size_t ws_size, hipStream_t stream) {
  const float* x     = (const float*)d_in[0];
  const float* l     = (const float*)d_in[1];
  const float* lmask = (const float*)d_in[2];
  const float* vis_w = (const float*)d_in[3];
  const float* vis_b = (const float*)d_in[4];
  const float* fq_w  = (const float*)d_in[5];
  const float* fq_b  = (const float*)d_in[6];
  const float* fk_w  = (const float*)d_in[7];
  const float* fk_b  = (const float*)d_in[8];
  const float* fv_w  = (const float*)d_in[9];
  const float* fv_b  = (const float*)d_in[10];
  const float* W_w   = (const float*)d_in[11];
  const float* W_b   = (const float*)d_in[12];
  const float* pm_w  = (const float*)d_in[13];
  const float* pm_b  = (const float*)d_in[14];

  char* ws = (char*)d_ws;
  const size_t SB = (size_t)MTOT * DIM * 2;  // one f16 [M,1024] buffer
  f16* Ah = (f16*)(ws);                      // x_f16 -> centered attn -> mm
  f16* Bh = (f16*)(ws + SB);                 // vis
  f16* Ch = (f16*)(ws + 2 * SB);             // q (f16)
  float* Df = (float*)(ws + 3 * SB);         // attn f32 -> lang_pre f32 (2*SB bytes)
  char* wsp = ws + 5 * SB;
  f16* vis_wh = (f16*)(wsp);
  f16* fq_wh  = (f16*)(wsp + (1 << 21));
  f16* W_wh   = (f16*)(wsp + 2 * (1 << 21));
  f16* pm_wh  = (f16*)(wsp + 3 * (1 << 21));
  float* Kout = (float*)(wsp + 4 * (1 << 21));
  float* Vout = (float*)(wsp + 4 * (1 << 21) + (1 << 20));
  float* st   = (float*)(wsp + 4 * (1 << 21) + 2 * (1 << 20));
  float* qmean = st;
  float* qrinv = st + 8192;
  float* amean = st + 16384;
  float* arinv = st + 24576;
  float* lmean = st + 32768;
  float* lrinv = st + 40960;
  float* psum  = (float*)(wsp + 4 * (1 << 21) + 3 * (1 << 20));  // CSPLIT*NB*DIM
  float* psq   = psum + (size_t)CSPLIT * NB * DIM;

  const int NCH_BIG = MTOT * DIM / 8;  // 5,607,424 chunks of 8
  const int NCH_W = DIM * DIM / 8;     // 131,072

  cvt_f32_f16<<<(NCH_BIG + 255) / 256, 256, 0, stream>>>(x, Ah, NCH_BIG);
  cvt_f32_f16<<<(NCH_W + 255) / 256, 256, 0, stream>>>(vis_w, vis_wh, NCH_W);
  cvt_f32_f16<<<(NCH_W + 255) / 256, 256, 0, stream>>>(fq_w, fq_wh, NCH_W);
  cvt_f32_f16<<<(NCH_W + 255) / 256, 256, 0, stream>>>(W_w, W_wh, NCH_W);
  cvt_f32_f16<<<(NCH_W + 255) / 256, 256, 0, stream>>>(pm_w, pm_wh, NCH_W);

  kv_gemm<<<dim3(16, 2, 8), 256, 0, stream>>>(l, lmask, fk_w, fk_b, fv_w, fv_b,
                                              Kout, Vout);

  // vis + q fused: one pass over A, 8 col-tiles (4 vis/gelu, 4 fq/plain).
  gemm256<0, 1><<<8 * MT256, 512, 0, stream>>>(
      Ah, vis_wh, vis_b, Bh, fq_wh, fq_b, Ch, MTOT);

  colstats_partial<f16><<<dim3(CSPLIT, NB), 256, 0, stream>>>(Ch, psum, psq);
  colstats_final<<<32, 256, 0, stream>>>(psum, psq, qmean, qrinv);

  attn_kernel<<<dim3((HW + 255) / 256, 8, 8), 256, 0, stream>>>(
      Ch, qmean, qrinv, Kout, Vout, lmask, Df);

  colstats_partial<float><<<dim3(CSPLIT, NB), 256, 0, stream>>>(Df, psum, psq);
  colstats_final<<<32, 256, 0, stream>>>(psum, psq, amean, arinv);
  center_kernel<<<(NCH_BIG + 255) / 256, 256, 0, stream>>>(Df, amean, Ah,
                                                           NCH_BIG);

  gemm256<2, -1><<<4 * MT256, 512, 0, stream>>>(
      Ah, W_wh, W_b, Df, nullptr, nullptr, nullptr, MTOT);  // lang_pre f32
  colstats_partial<float><<<dim3(CSPLIT, NB), 256, 0, stream>>>(Df, psum, psq);
  colstats_final<<<32, 256, 0, stream>>>(psum, psq, lmean, lrinv);
  fuse_kernel<<<(NCH_BIG + 255) / 256, 256, 0, stream>>>(Bh, Df, lmean, lrinv,
                                                         Ah, NCH_BIG);

  gemm256<3, -1><<<4 * MT256, 512, 0, stream>>>(
      Ah, pm_wh, pm_b, d_out, nullptr, nullptr, nullptr, MTOT);  // output
}

// Round 6
// 1474.019 us; speedup vs baseline: 1.0051x; 1.0051x over previous
//
#include <hip/hip_runtime.h>

typedef _Float16 f16;
typedef _Float16 f16x4 __attribute__((ext_vector_type(4)));
typedef _Float16 f16x8 __attribute__((ext_vector_type(8)));
typedef float f32x4 __attribute__((ext_vector_type(4)));

#define NB   8
#define HW   5476
#define NL   32
#define DIM  1024
#define LIN  768
#define MTOT (NB * HW)            // 43808
#define MT256 ((MTOT + 255) / 256)  // 172 row-tiles of 256
#define CSPLIT 128                // colstats row-splits per batch
#define ASPLIT 22                 // attn-fused colsum partials per batch

// ---------------------------------------------------------------- utilities

__device__ __forceinline__ void g2l16(const void* g, void* l) {
#if __has_builtin(__builtin_amdgcn_global_load_lds)
  __builtin_amdgcn_global_load_lds(
      (const __attribute__((address_space(1))) void*)g,
      (__attribute__((address_space(3))) void*)l, 16, 0, 0);
#else
  const int lane = threadIdx.x & 63;
  *(uint4*)((char*)l + lane * 16) = *(const uint4*)g;
#endif
}

__device__ __forceinline__ float gelu_f(float x) {
  return 0.5f * x * (1.0f + erff(x * 0.70710678118654752f));
}

#define WAITV(N) asm volatile("s_waitcnt vmcnt(" #N ")" ::: "memory")
__device__ __forceinline__ void barrier_nf() {
  asm volatile("s_barrier" ::: "memory");  // raw barrier, no vmcnt drain
}

// Pair-XOR LDS swizzle for BK=32 tiles (64B rows, 128B pair regions).
// Logical (row r, 16B k-chunk q in 0..3) lives at pair p=r>>1,
// chunk c' = (((r&1)<<2)|q) ^ (p&7). Involution applied on the
// global_load_lds SOURCE address and on the ds_read address. Verified:
// SQ_LDS_BANK_CONFLICT = 0 on hardware.
__device__ __forceinline__ int swz32(int r, int q) {
  const int p = r >> 1;
  const int c = (((r & 1) << 2) | q) ^ (p & 7);
  return p * 64 + c * 8;  // element offset (f16)
}

// ---------------------------------------------------------------- big GEMM
// C[M,N] = A[M,K] * W[N,K]^T (+bias, epilogue). K = N = 1024.
// R3-proven structure: 256x256 tile, BK=32, 8 waves (2M x 4N), FOUR LDS
// buffers (128 KiB), depth-3 prefetch, counted vmcnt(8) (never 0 until
// tail), ONE barrier per K-step, setprio around the MFMA cluster.
// Epilogue: j-innermost so each row's 4 chunks are consecutive stores
// (128B f16 / 256B f32 contiguous per row -> kills write amplification).
// EPI: 0 = gelu->f16, 1 = plain->f16, 2 = plain->f32, 3 = gelu->f32
// EPI2 >= 0: dual-output mode; blocks with nt >= 4 use W2/bias2/out2.
// T1: bijective XCD swizzle, mt fastest within an XCD chunk.
template <int EPI, int EPI2>
__global__ __launch_bounds__(512, 2) void gemm256(
    const f16* __restrict__ A, const f16* __restrict__ W,
    const float* __restrict__ bias, void* __restrict__ out,
    const f16* __restrict__ W2, const float* __restrict__ bias2,
    void* __restrict__ out2, int M) {
  constexpr int K = 1024, N = 1024;
  constexpr int KT = K / 32;               // 32 K-steps
  constexpr int NT = (EPI2 >= 0) ? 8 : 4;  // 256-col tiles (dual: 4 + 4)
  constexpr int NWG = NT * MT256;
  constexpr int CHUNK = NWG / 8;
  __shared__ f16 lds[4][2][256 * 32];  // [buf][A=0/B=1][swizzled]

  // T1: xcd = blockIdx.x % 8 (hardware round-robin). mt fast, nt slow.
  const int L = blockIdx.x;
  const int w = (L & 7) * CHUNK + (L >> 3);
  const int mt = w % MT256;
  int nt = w / MT256;
  const f16* Wp = W;
  const float* bp = bias;
  void* op = out;
  bool second = false;
  if constexpr (EPI2 >= 0) {
    if (nt >= 4) {
      nt -= 4;
      Wp = W2;
      bp = bias2;
      op = out2;
      second = true;
    }
  }

  const int tid = threadIdx.x;
  const int wave = tid >> 6, lane = tid & 63;
  const int m0 = mt * 256, n0 = nt * 256;
  const int wm = (wave >> 2) * 128;  // 2 waves in M
  const int wn = (wave & 3) * 64;    // 4 waves in N
  const int fr = lane & 15, fq = lane >> 4;

  f32x4 acc[8][4];
#pragma unroll
  for (int i = 0; i < 8; ++i)
#pragma unroll
    for (int j = 0; j < 4; ++j) acc[i][j] = (f32x4){0.f, 0.f, 0.f, 0.f};

  // Stage-side source mapping (per 1KB region = 16 rows): lane writes LDS
  // byte lane*16 -> pair p_local = lane>>3, chunk c' = lane&7; it must
  // source logical chunk c = c' ^ p_local -> row offset and k-chunk:
  const int plocal = lane >> 3;
  const int csw = (lane & 7) ^ plocal;
  const int rofs = plocal * 2 + (csw >> 2);  // row within 16-row region
  const int qofs = (csw & 3) * 8;            // element offset within row

  // stage one K-tile: 4 g2l16/thread (2 A regions + 2 B regions per wave)
  auto stage = [&](int t) {
    const int buf = t & 3;
    const int k0 = t * 32;
    f16* Ab = &lds[buf][0][0];
    f16* Bb = &lds[buf][1][0];
#pragma unroll
    for (int la = 0; la < 2; ++la) {
      const int rg = wave * 2 + la;  // 16-row region
      int gm = m0 + rg * 16 + rofs;
      if (gm > M - 1) gm = M - 1;
      g2l16(A + (size_t)gm * K + k0 + qofs, &Ab[rg * 512]);
    }
#pragma unroll
    for (int la = 0; la < 2; ++la) {
      const int rg = wave * 2 + la;
      const int gn = n0 + rg * 16 + rofs;
      g2l16(Wp + (size_t)gn * K + k0 + qofs, &Bb[rg * 512]);
    }
  };

  // one K-step of compute: 12 ds_read_b128 + 32 MFMA
  auto compute = [&](int t) {
    const f16* Ab = &lds[t & 3][0][0];
    const f16* Bb = &lds[t & 3][1][0];
    f16x8 af[8], bf[4];
#pragma unroll
    for (int i = 0; i < 8; ++i)
      af[i] = *(const f16x8*)&Ab[swz32(wm + i * 16 + fr, fq)];
#pragma unroll
    for (int j = 0; j < 4; ++j)
      bf[j] = *(const f16x8*)&Bb[swz32(wn + j * 16 + fr, fq)];
    __builtin_amdgcn_s_setprio(1);
#pragma unroll
    for (int i = 0; i < 8; ++i)
#pragma unroll
      for (int j = 0; j < 4; ++j)
        acc[i][j] = __builtin_amdgcn_mfma_f32_16x16x32_f16(af[i], bf[j],
                                                           acc[i][j], 0, 0, 0);
    __builtin_amdgcn_s_setprio(0);
  };

  // prologue: 3 tiles in flight
  stage(0);
  stage(1);
  stage(2);
  // main loop: wait tile t (vmcnt(8) = tiles t+1,t+2 may stay in flight),
  // barrier (tile t visible; prior reads of buf[(t+3)&3] retired), stage
  // t+3, compute t. Single barrier per K-step; no vmcnt(0) drain.
#pragma unroll 4
  for (int t = 0; t < KT - 4; ++t) {
    WAITV(8);
    barrier_nf();
    stage(t + 3);
    compute(t);
  }
  WAITV(8); barrier_nf(); stage(KT - 1); compute(KT - 4);
  WAITV(8); barrier_nf(); compute(KT - 3);
  WAITV(4); barrier_nf(); compute(KT - 2);
  WAITV(0); barrier_nf(); compute(KT - 1);

  // Epilogue. C/D layout: col = lane&15, row = (lane>>4)*4 + reg.
  const bool do_gelu = second ? (EPI2 == 0 || EPI2 == 3) : (EPI == 0 || EPI == 3);
  const bool to_f16 = second ? (EPI2 <= 1) : (EPI <= 1);
  const int row0 = m0 + wm + fq * 4;
  const int col0 = n0 + wn + fr;
  float bv[4];
#pragma unroll
  for (int j = 0; j < 4; ++j) bv[j] = bp[col0 + j * 16];
#pragma unroll
  for (int i = 0; i < 8; ++i) {
#pragma unroll
    for (int r = 0; r < 4; ++r) {
      const int row = row0 + i * 16 + r;
      if (row < M) {
#pragma unroll
        for (int j = 0; j < 4; ++j) {  // j innermost: contiguous row chunks
          float v = acc[i][j][r] + bv[j];
          if (do_gelu) v = gelu_f(v);
          if (to_f16)
            ((f16*)op)[(size_t)row * N + col0 + j * 16] = (f16)v;
          else
            ((float*)op)[(size_t)row * N + col0 + j * 16] = v;
        }
      }
    }
  }
}

// ---------------------------------------------------------------- fp32 -> fp16
__global__ void cvt_f32_f16(const float* __restrict__ in, f16* __restrict__ out,
                            int nchunks) {
  const int i = blockIdx.x * 256 + threadIdx.x;
  if (i >= nchunks) return;
  const float4* p = (const float4*)in + (size_t)i * 2;
  const float4 a = p[0], b = p[1];
  f16x8 o = {(f16)a.x, (f16)a.y, (f16)a.z, (f16)a.w,
             (f16)b.x, (f16)b.y, (f16)b.z, (f16)b.w};
  *((f16x8*)out + i) = o;
}

// ---------------------------------------------------------------- column stats
template <typename T>
__global__ __launch_bounds__(256) void colstats_partial(
    const T* __restrict__ X, float* __restrict__ psum,
    float* __restrict__ psq) {
  const int b = blockIdx.y;
  const int sp = blockIdx.x;
  const int c = threadIdx.x * 4;  // 4 columns per thread
  constexpr int CHUNK = (HW + CSPLIT - 1) / CSPLIT;  // 43
  const int r0 = sp * CHUNK;
  const int r1 = (r0 + CHUNK < HW) ? r0 + CHUNK : HW;

  float s0 = 0.f, s1 = 0.f, s2 = 0.f, s3 = 0.f;
  float q0 = 0.f, q1 = 0.f, q2 = 0.f, q3 = 0.f;
  const T* base = X + ((size_t)b * HW + r0) * DIM + c;
  for (int r = r0; r < r1; ++r) {
    float v0, v1, v2, v3;
    if constexpr (sizeof(T) == 2) {
      const f16x4 v = *(const f16x4*)base;
      v0 = (float)v[0]; v1 = (float)v[1]; v2 = (float)v[2]; v3 = (float)v[3];
    } else {
      const float4 v = *(const float4*)base;
      v0 = v.x; v1 = v.y; v2 = v.z; v3 = v.w;
    }
    s0 += v0; s1 += v1; s2 += v2; s3 += v3;
    q0 += v0 * v0; q1 += v1 * v1; q2 += v2 * v2; q3 += v3 * v3;
    base += DIM;
  }
  const size_t o = ((size_t)sp * NB + b) * DIM + c;
  *(float4*)&psum[o] = make_float4(s0, s1, s2, s3);
  *(float4*)&psq[o] = make_float4(q0, q1, q2, q3);
}

__global__ __launch_bounds__(256) void colstats_final(
    const float* __restrict__ psum, const float* __restrict__ psq,
    float* __restrict__ mean, float* __restrict__ rinv) {
  const int i = blockIdx.x * 256 + threadIdx.x;  // over NB*DIM = 8192
  float s = 0.f, q = 0.f;
  for (int sp = 0; sp < CSPLIT; ++sp) {
    s += psum[(size_t)sp * NB * DIM + i];
    q += psq[(size_t)sp * NB * DIM + i];
  }
  const float m = s * (1.0f / HW);
  const float var = q * (1.0f / HW) - m * m;
  mean[i] = m;
  rinv[i] = rsqrtf(var + 1e-5f);
}

// reduce attn-fused partial colsums (ASPLIT splits) -> mean only
__global__ __launch_bounds__(256) void asum_final(
    const float* __restrict__ psum, float* __restrict__ mean) {
  const int i = blockIdx.x * 256 + threadIdx.x;  // over NB*DIM = 8192
  float s = 0.f;
  for (int sp = 0; sp < ASPLIT; ++sp) s += psum[(size_t)sp * NB * DIM + i];
  mean[i] = s * (1.0f / HW);
}

// ---------------------------------------------------------------- k/v small GEMM
__global__ __launch_bounds__(256) void kv_gemm(
    const float* __restrict__ l, const float* __restrict__ lmask,
    const float* __restrict__ wk, const float* __restrict__ bk,
    const float* __restrict__ wv, const float* __restrict__ bv,
    float* __restrict__ Kout, float* __restrict__ Vout) {
  const int b = blockIdx.z;
  const int o0 = blockIdx.x * 64;
  const float* w = blockIdx.y ? wv : wk;
  const float* bb = blockIdx.y ? bv : bk;
  float* out = blockIdx.y ? Vout : Kout;

  __shared__ float wl[64 * 129];
  __shared__ float ll[32 * 129];
  const int tid = threadIdx.x;
  const int o = tid & 63, ng = tid >> 6;  // each thread: 1 o x 8 n
  float acc[8];
#pragma unroll
  for (int j = 0; j < 8; ++j) acc[j] = 0.f;

  for (int kc = 0; kc < LIN; kc += 128) {
    for (int e = tid; e < 64 * 128; e += 256)
      wl[(e >> 7) * 129 + (e & 127)] =
          w[(size_t)(o0 + (e >> 7)) * LIN + kc + (e & 127)];
    for (int e = tid; e < 32 * 128; e += 256)
      ll[(e >> 7) * 129 + (e & 127)] =
          l[(size_t)b * NL * LIN + (size_t)(e >> 7) * LIN + kc + (e & 127)];
    __syncthreads();
    for (int k = 0; k < 128; ++k) {
      const float wv_ = wl[o * 129 + k];
#pragma unroll
      for (int j = 0; j < 8; ++j) acc[j] += wv_ * ll[(ng * 8 + j) * 129 + k];
    }
    __syncthreads();
  }
  const float bval = bb[o0 + o];
#pragma unroll
  for (int j = 0; j < 8; ++j) {
    const int n = ng * 8 + j;
    out[((size_t)b * DIM + o0 + o) * NL + n] =
        (acc[j] + bval) * lmask[b * NL + n];
  }
}

// ---------------------------------------------------------------- attention
// Per (b,h,m): scores over 32 keys (dk=128), softmax, weighted sum of v.
// Fused: per-block partial column sums of the output (for amean) -> psum.
// Blocks are batch-clean (grid z = batch), so partials are per (sp, b).
__global__ __launch_bounds__(256) void attn_kernel(
    const f16* __restrict__ Q, const float* __restrict__ qmean,
    const float* __restrict__ qrinv, const float* __restrict__ Kk,
    const float* __restrict__ Vv, const float* __restrict__ lmask,
    float* __restrict__ Out, float* __restrict__ psum) {
  const int b = blockIdx.z, h = blockIdx.y;
  __shared__ float ks[128 * NL], vs[128 * NL], qm[128], qr[128], bs[NL];
  const int tid = threadIdx.x;
  const float* kbase = Kk + ((size_t)b * DIM + h * 128) * NL;
  const float* vbase = Vv + ((size_t)b * DIM + h * 128) * NL;
  for (int i = tid; i < 128 * NL; i += 256) {
    ks[i] = kbase[i];
    vs[i] = vbase[i];
  }
  if (tid < 128) {
    qm[tid] = qmean[b * DIM + h * 128 + tid];
    qr[tid] = qrinv[b * DIM + h * 128 + tid];
  }
  if (tid < NL) bs[tid] = (lmask[b * NL + tid] - 1.0f) * 10000.0f;
  __syncthreads();

  const int mloc = blockIdx.x * 256 + tid;
  const bool valid = mloc < HW;
  const int mc = valid ? mloc : HW - 1;
  const size_t m = (size_t)b * HW + mc;
  const f16* qrow = Q + m * DIM + h * 128;

  float sc[32];
#pragma unroll
  for (int n = 0; n < 32; ++n) sc[n] = 0.f;

  for (int d8 = 0; d8 < 16; ++d8) {
    const f16x8 qv = *(const f16x8*)(qrow + d8 * 8);
#pragma unroll
    for (int j = 0; j < 8; ++j) {
      const int d = d8 * 8 + j;
      const float qd = ((float)qv[j] - qm[d]) * qr[d];
      const float4* kr = (const float4*)&ks[d * 32];
#pragma unroll
      for (int n4 = 0; n4 < 8; ++n4) {
        const float4 kk = kr[n4];
        sc[n4 * 4 + 0] += qd * kk.x;
        sc[n4 * 4 + 1] += qd * kk.y;
        sc[n4 * 4 + 2] += qd * kk.z;
        sc[n4 * 4 + 3] += qd * kk.w;
      }
    }
  }
  float mx = -1e30f;
#pragma unroll
  for (int n = 0; n < 32; ++n) {
    sc[n] = sc[n] * 0.03125f + bs[n];  // * KC^-0.5 then masked bias
    mx = fmaxf(mx, sc[n]);
  }
  float sum = 0.f;
#pragma unroll
  for (int n = 0; n < 32; ++n) {
    sc[n] = __expf(sc[n] - mx);
    sum += sc[n];
  }
  const float rs = 1.0f / sum;

  float* orow = Out + m * DIM + h * 128;
  float* pbase = psum + ((size_t)blockIdx.x * NB + b) * DIM + h * 128;
  for (int dv8 = 0; dv8 < 16; ++dv8) {
    float ov[8];
#pragma unroll
    for (int j = 0; j < 8; ++j) {
      const float4* vr = (const float4*)&vs[(dv8 * 8 + j) * 32];
      float a = 0.f;
#pragma unroll
      for (int n4 = 0; n4 < 8; ++n4) {
        const float4 vv = vr[n4];
        a += sc[n4 * 4 + 0] * vv.x + sc[n4 * 4 + 1] * vv.y +
             sc[n4 * 4 + 2] * vv.z + sc[n4 * 4 + 3] * vv.w;
      }
      ov[j] = a * rs;
    }
    if (valid) {
      float4* op = (float4*)(orow + dv8 * 8);
      op[0] = make_float4(ov[0], ov[1], ov[2], ov[3]);
      op[1] = make_float4(ov[4], ov[5], ov[6], ov[7]);
    }
    // wave-reduce column partial sums, one atomicAdd per wave per column
#pragma unroll
    for (int j = 0; j < 8; ++j) {
      float v = valid ? ov[j] : 0.f;
      v += __shfl_down(v, 32);
      v += __shfl_down(v, 16);
      v += __shfl_down(v, 8);
      v += __shfl_down(v, 4);
      v += __shfl_down(v, 2);
      v += __shfl_down(v, 1);
      if ((tid & 63) == 0) atomicAdd(&pbase[dv8 * 8 + j], v);
    }
  }
}

// ---------------------------------------------------------------- center (attn - colmean) -> f16
__global__ void center_kernel(const float* __restrict__ X,
                              const float* __restrict__ mean,
                              f16* __restrict__ out, int nchunks) {
  const int i = blockIdx.x * 256 + threadIdx.x;
  if (i >= nchunks) return;
  const size_t e = (size_t)i * 8;
  const int mrow = (int)(e >> 10);
  const int o = (int)(e & 1023);
  const int b = mrow / HW;
  const float4* p = (const float4*)(X + e);
  const float4 a = p[0], c = p[1];
  const float* mn = mean + b * DIM + o;
  f16x8 r = {(f16)(a.x - mn[0]), (f16)(a.y - mn[1]), (f16)(a.z - mn[2]),
             (f16)(a.w - mn[3]), (f16)(c.x - mn[4]), (f16)(c.y - mn[5]),
             (f16)(c.z - mn[6]), (f16)(c.w - mn[7])};
  *((f16x8*)out + i) = r;
}

// ---------------------------------------------------------------- fuse: mm = vis * inorm(lang_pre)
__global__ void fuse_kernel(const f16* __restrict__ vis,
                            const float* __restrict__ lang,
                            const float* __restrict__ mean,
                            const float* __restrict__ rinv,
                            f16* __restrict__ out, int nchunks) {
  const int i = blockIdx.x * 256 + threadIdx.x;
  if (i >= nchunks) return;
  const size_t e = (size_t)i * 8;
  const int mrow = (int)(e >> 10);
  const int o = (int)(e & 1023);
  const int b = mrow / HW;
  const f16x8 v = *((const f16x8*)vis + i);
  const float4* p = (const float4*)(lang + e);
  const float4 a = p[0], c = p[1];
  const float lv[8] = {a.x, a.y, a.z, a.w, c.x, c.y, c.z, c.w};
  const float* mn = mean + b * DIM + o;
  const float* ri = rinv + b * DIM + o;
  f16x8 r;
#pragma unroll
  for (int j = 0; j < 8; ++j)
    r[j] = (f16)((float)v[j] * ((lv[j] - mn[j]) * ri[j]));
  *((f16x8*)out + i) = r;
}

// ---------------------------------------------------------------- launch
extern "C" void kernel_launch(void* const* d_in, const int* in_sizes, int n_in,
                              void* d_out, int out_size, void* d_ws,
                              size_t ws_size, hipStream_t stream) {
  const float* x     = (const float*)d_in[0];
  const float* l     = (const float*)d_in[1];
  const float* lmask = (const float*)d_in[2];
  const float* vis_w = (const float*)d_in[3];
  const float* vis_b = (const float*)d_in[4];
  const float* fq_w  = (const float*)d_in[5];
  const float* fq_b  = (const float*)d_in[6];
  const float* fk_w  = (const float*)d_in[7];
  const float* fk_b  = (const float*)d_in[8];
  const float* fv_w  = (const float*)d_in[9];
  const float* fv_b  = (const float*)d_in[10];
  const float* W_w   = (const float*)d_in[11];
  const float* W_b   = (const float*)d_in[12];
  const float* pm_w  = (const float*)d_in[13];
  const float* pm_b  = (const float*)d_in[14];

  char* ws = (char*)d_ws;
  const size_t SB = (size_t)MTOT * DIM * 2;  // one f16 [M,1024] buffer
  f16* Ah = (f16*)(ws);                      // x_f16 -> centered attn -> mm
  f16* Bh = (f16*)(ws + SB);                 // vis
  f16* Ch = (f16*)(ws + 2 * SB);             // q (f16)
  float* Df = (float*)(ws + 3 * SB);         // attn f32 -> lang_pre f32 (2*SB bytes)
  char* wsp = ws + 5 * SB;
  f16* vis_wh = (f16*)(wsp);
  f16* fq_wh  = (f16*)(wsp + (1 << 21));
  f16* W_wh   = (f16*)(wsp + 2 * (1 << 21));
  f16* pm_wh  = (f16*)(wsp + 3 * (1 << 21));
  float* Kout = (float*)(wsp + 4 * (1 << 21));
  float* Vout = (float*)(wsp + 4 * (1 << 21) + (1 << 20));
  float* st   = (float*)(wsp + 4 * (1 << 21) + 2 * (1 << 20));
  float* qmean = st;
  float* qrinv = st + 8192;
  float* amean = st + 16384;
  float* arinv = st + 24576;
  float* lmean = st + 32768;
  float* lrinv = st + 40960;
  float* psum  = (float*)(wsp + 4 * (1 << 21) + 3 * (1 << 20));  // CSPLIT*NB*DIM
  float* psq   = psum + (size_t)CSPLIT * NB * DIM;

  const int NCH_BIG = MTOT * DIM / 8;  // 5,607,424 chunks of 8
  const int NCH_W = DIM * DIM / 8;     // 131,072

  cvt_f32_f16<<<(NCH_BIG + 255) / 256, 256, 0, stream>>>(x, Ah, NCH_BIG);
  cvt_f32_f16<<<(NCH_W + 255) / 256, 256, 0, stream>>>(vis_w, vis_wh, NCH_W);
  cvt_f32_f16<<<(NCH_W + 255) / 256, 256, 0, stream>>>(fq_w, fq_wh, NCH_W);
  cvt_f32_f16<<<(NCH_W + 255) / 256, 256, 0, stream>>>(W_w, W_wh, NCH_W);
  cvt_f32_f16<<<(NCH_W + 255) / 256, 256, 0, stream>>>(pm_w, pm_wh, NCH_W);

  kv_gemm<<<dim3(16, 2, 8), 256, 0, stream>>>(l, lmask, fk_w, fk_b, fv_w, fv_b,
                                              Kout, Vout);

  // vis + q fused: one pass over A, 8 col-tiles (4 vis/gelu, 4 fq/plain).
  gemm256<0, 1><<<8 * MT256, 512, 0, stream>>>(
      Ah, vis_wh, vis_b, Bh, fq_wh, fq_b, Ch, MTOT);

  colstats_partial<f16><<<dim3(CSPLIT, NB), 256, 0, stream>>>(Ch, psum, psq);
  colstats_final<<<32, 256, 0, stream>>>(psum, psq, qmean, qrinv);

  // attn with fused partial colsums (psum reused; zero first)
  hipMemsetAsync(psum, 0, (size_t)ASPLIT * NB * DIM * sizeof(float), stream);
  attn_kernel<<<dim3((HW + 255) / 256, 8, 8), 256, 0, stream>>>(
      Ch, qmean, qrinv, Kout, Vout, lmask, Df, psum);
  asum_final<<<32, 256, 0, stream>>>(psum, amean);
  center_kernel<<<(NCH_BIG + 255) / 256, 256, 0, stream>>>(Df, amean, Ah,
                                                           NCH_BIG);

  gemm256<2, -1><<<4 * MT256, 512, 0, stream>>>(
      Ah, W_wh, W_b, Df, nullptr, nullptr, nullptr, MTOT);  // lang_pre f32
  colstats_partial<float><<<dim3(CSPLIT, NB), 256, 0, stream>>>(Df, psum, psq);
  colstats_final<<<32, 256, 0, stream>>>(psum, psq, lmean, lrinv);
  fuse_kernel<<<(NCH_BIG + 255) / 256, 256, 0, stream>>>(Bh, Df, lmean, lrinv,
                                                         Ah, NCH_BIG);

  gemm256<3, -1><<<4 * MT256, 512, 0, stream>>>(
      Ah, pm_wh, pm_b, d_out, nullptr, nullptr, nullptr, MTOT);  // output
}

// Round 7
// 1280.976 us; speedup vs baseline: 1.1566x; 1.1507x over previous
//
#include <hip/hip_runtime.h>

typedef _Float16 f16;
typedef _Float16 f16x4 __attribute__((ext_vector_type(4)));
typedef _Float16 f16x8 __attribute__((ext_vector_type(8)));
typedef float f32x4 __attribute__((ext_vector_type(4)));

#define NB   8
#define HW   5476
#define NL   32
#define DIM  1024
#define LIN  768
#define MTOT (NB * HW)            // 43808
#define MT256 ((MTOT + 255) / 256)  // 172 row-tiles of 256

// ---------------------------------------------------------------- utilities

__device__ __forceinline__ void g2l16(const void* g, void* l) {
#if __has_builtin(__builtin_amdgcn_global_load_lds)
  __builtin_amdgcn_global_load_lds(
      (const __attribute__((address_space(1))) void*)g,
      (__attribute__((address_space(3))) void*)l, 16, 0, 0);
#else
  const int lane = threadIdx.x & 63;
  *(uint4*)((char*)l + lane * 16) = *(const uint4*)g;
#endif
}

__device__ __forceinline__ float gelu_f(float x) {
  return 0.5f * x * (1.0f + erff(x * 0.70710678118654752f));
}

#define WAITV(N) asm volatile("s_waitcnt vmcnt(" #N ")" ::: "memory")
__device__ __forceinline__ void barrier_nf() {
  asm volatile("s_barrier" ::: "memory");  // raw barrier, no vmcnt drain
}

// Pair-XOR LDS swizzle for BK=32 tiles. Verified SQ_LDS_BANK_CONFLICT = 0.
__device__ __forceinline__ int swz32(int r, int q) {
  const int p = r >> 1;
  const int c = (((r & 1) << 2) | q) ^ (p & 7);
  return p * 64 + c * 8;  // element offset (f16)
}

// ---------------------------------------------------------------- big GEMM
// C[M,N] = A[M,K] * W[N,K]^T (+bias, epilogue). K = N = 1024.
// R3-proven schedule: 256x256 tile, BK=32, 8 waves (2M x 4N), 4 LDS buffers
// (128 KiB), depth-3 prefetch, counted vmcnt(8), ONE barrier per K-step,
// setprio around MFMA. j-innermost epilogue (WRITE = ideal, verified R6).
// T1: bijective XCD swizzle, nt FASTEST (verified best: FETCH 242 vs 363).
// EPI: 0 = gelu->f16, 1 = plain->f16, 2 = plain->f32, 3 = gelu->f32
// EPI2 >= 0: dual mode; blocks with nt >= 4 use W2/bias2/out2.
// STATS: 0 none; 1 = column sum/sumsq of SECOND output; 2 = of primary.
// Stats are per-batch (batch = row/HW; a tile straddles <= 1 boundary),
// accumulated f32 pre-cast, wave-reduced, atomicAdd into ssum/ssq[b*DIM+c].
template <int EPI, int EPI2, int STATS>
__global__ __launch_bounds__(512, 2) void gemm256(
    const f16* __restrict__ A, const f16* __restrict__ W,
    const float* __restrict__ bias, void* __restrict__ out,
    const f16* __restrict__ W2, const float* __restrict__ bias2,
    void* __restrict__ out2, float* __restrict__ ssum,
    float* __restrict__ ssq, int M) {
  constexpr int K = 1024, N = 1024;
  constexpr int KT = K / 32;               // 32 K-steps
  constexpr int NT = (EPI2 >= 0) ? 8 : 4;  // 256-col tiles (dual: 4 + 4)
  constexpr int NWG = NT * MT256;
  constexpr int CHUNK = NWG / 8;
  __shared__ f16 lds[4][2][256 * 32];  // [buf][A=0/B=1][swizzled]

  // T1: xcd = blockIdx.x % 8. nt fastest (R3 mapping, FETCH-verified).
  const int L = blockIdx.x;
  const int w = (L & 7) * CHUNK + (L >> 3);
  const int mt = w / NT;
  int nt = w % NT;
  const f16* Wp = W;
  const float* bp = bias;
  void* op = out;
  bool second = false;
  if constexpr (EPI2 >= 0) {
    if (nt >= 4) {
      nt -= 4;
      Wp = W2;
      bp = bias2;
      op = out2;
      second = true;
    }
  }

  const int tid = threadIdx.x;
  const int wave = tid >> 6, lane = tid & 63;
  const int m0 = mt * 256, n0 = nt * 256;
  const int wm = (wave >> 2) * 128;  // 2 waves in M
  const int wn = (wave & 3) * 64;    // 4 waves in N
  const int fr = lane & 15, fq = lane >> 4;

  f32x4 acc[8][4];
#pragma unroll
  for (int i = 0; i < 8; ++i)
#pragma unroll
    for (int j = 0; j < 4; ++j) acc[i][j] = (f32x4){0.f, 0.f, 0.f, 0.f};

  // Stage-side source mapping for the pair-XOR swizzle.
  const int plocal = lane >> 3;
  const int csw = (lane & 7) ^ plocal;
  const int rofs = plocal * 2 + (csw >> 2);
  const int qofs = (csw & 3) * 8;

  auto stage = [&](int t) {
    const int buf = t & 3;
    const int k0 = t * 32;
    f16* Ab = &lds[buf][0][0];
    f16* Bb = &lds[buf][1][0];
#pragma unroll
    for (int la = 0; la < 2; ++la) {
      const int rg = wave * 2 + la;  // 16-row region
      int gm = m0 + rg * 16 + rofs;
      if (gm > M - 1) gm = M - 1;
      g2l16(A + (size_t)gm * K + k0 + qofs, &Ab[rg * 512]);
    }
#pragma unroll
    for (int la = 0; la < 2; ++la) {
      const int rg = wave * 2 + la;
      const int gn = n0 + rg * 16 + rofs;
      g2l16(Wp + (size_t)gn * K + k0 + qofs, &Bb[rg * 512]);
    }
  };

  auto compute = [&](int t) {
    const f16* Ab = &lds[t & 3][0][0];
    const f16* Bb = &lds[t & 3][1][0];
    f16x8 af[8], bf[4];
#pragma unroll
    for (int i = 0; i < 8; ++i)
      af[i] = *(const f16x8*)&Ab[swz32(wm + i * 16 + fr, fq)];
#pragma unroll
    for (int j = 0; j < 4; ++j)
      bf[j] = *(const f16x8*)&Bb[swz32(wn + j * 16 + fr, fq)];
    __builtin_amdgcn_s_setprio(1);
#pragma unroll
    for (int i = 0; i < 8; ++i)
#pragma unroll
      for (int j = 0; j < 4; ++j)
        acc[i][j] = __builtin_amdgcn_mfma_f32_16x16x32_f16(af[i], bf[j],
                                                           acc[i][j], 0, 0, 0);
    __builtin_amdgcn_s_setprio(0);
  };

  stage(0);
  stage(1);
  stage(2);
#pragma unroll 4
  for (int t = 0; t < KT - 4; ++t) {
    WAITV(8);
    barrier_nf();
    stage(t + 3);
    compute(t);
  }
  WAITV(8); barrier_nf(); stage(KT - 1); compute(KT - 4);
  WAITV(8); barrier_nf(); compute(KT - 3);
  WAITV(4); barrier_nf(); compute(KT - 2);
  WAITV(0); barrier_nf(); compute(KT - 1);

  // Epilogue. C/D layout: col = lane&15, row = (lane>>4)*4 + reg.
  const bool do_gelu = second ? (EPI2 == 0 || EPI2 == 3) : (EPI == 0 || EPI == 3);
  const bool to_f16 = second ? (EPI2 <= 1) : (EPI <= 1);
  const bool do_stats = (STATS == 2) || (STATS == 1 && second);
  const int row0 = m0 + wm + fq * 4;
  const int col0 = n0 + wn + fr;
  float bv[4];
#pragma unroll
  for (int j = 0; j < 4; ++j) bv[j] = bp[col0 + j * 16];

  const int bA = m0 / HW;
  const int bnd = (bA + 1) * HW;  // first row of next batch
  const bool straddle = (m0 + 255 >= bnd) && (bA + 1 < NB);
  float sA[4] = {0, 0, 0, 0}, qA[4] = {0, 0, 0, 0};
  float sB[4] = {0, 0, 0, 0}, qB[4] = {0, 0, 0, 0};

#pragma unroll
  for (int i = 0; i < 8; ++i) {
#pragma unroll
    for (int r = 0; r < 4; ++r) {
      const int row = row0 + i * 16 + r;
      if (row < M) {
#pragma unroll
        for (int j = 0; j < 4; ++j) {  // j innermost: contiguous row chunks
          float v = acc[i][j][r] + bv[j];
          if (do_gelu) v = gelu_f(v);
          if constexpr (STATS != 0) {
            if (do_stats) {
              if (row < bnd) { sA[j] += v; qA[j] += v * v; }
              else           { sB[j] += v; qB[j] += v * v; }
            }
          }
          if (to_f16)
            ((f16*)op)[(size_t)row * N + col0 + j * 16] = (f16)v;
          else
            ((float*)op)[(size_t)row * N + col0 + j * 16] = v;
        }
      }
    }
  }

  if constexpr (STATS != 0) {
    if (do_stats) {
#pragma unroll
      for (int j = 0; j < 4; ++j) {
        float s = sA[j], q = qA[j];
        s += __shfl_down(s, 16); s += __shfl_down(s, 32);
        q += __shfl_down(q, 16); q += __shfl_down(q, 32);
        if (lane < 16) {
          atomicAdd(&ssum[(size_t)bA * DIM + col0 + j * 16], s);
          atomicAdd(&ssq[(size_t)bA * DIM + col0 + j * 16], q);
        }
      }
      if (straddle) {
#pragma unroll
        for (int j = 0; j < 4; ++j) {
          float s = sB[j], q = qB[j];
          s += __shfl_down(s, 16); s += __shfl_down(s, 32);
          q += __shfl_down(q, 16); q += __shfl_down(q, 32);
          if (lane < 16) {
            atomicAdd(&ssum[(size_t)(bA + 1) * DIM + col0 + j * 16], s);
            atomicAdd(&ssq[(size_t)(bA + 1) * DIM + col0 + j * 16], q);
          }
        }
      }
    }
  }
}

// ---------------------------------------------------------------- fp32 -> fp16
__global__ void cvt_f32_f16(const float* __restrict__ in, f16* __restrict__ out,
                            int nchunks) {
  const int i = blockIdx.x * 256 + threadIdx.x;
  if (i >= nchunks) return;
  const float4* p = (const float4*)in + (size_t)i * 2;
  const float4 a = p[0], b = p[1];
  f16x8 o = {(f16)a.x, (f16)a.y, (f16)a.z, (f16)a.w,
             (f16)b.x, (f16)b.y, (f16)b.z, (f16)b.w};
  *((f16x8*)out + i) = o;
}

// ---------------------------------------------------------------- stat finals
__global__ __launch_bounds__(256) void mean_rinv_final(
    const float* __restrict__ sum, const float* __restrict__ sq,
    float* __restrict__ mean, float* __restrict__ rinv) {
  const int i = blockIdx.x * 256 + threadIdx.x;  // over NB*DIM = 8192
  const float m = sum[i] * (1.0f / HW);
  mean[i] = m;
  rinv[i] = rsqrtf(sq[i] * (1.0f / HW) - m * m + 1e-5f);
}

__global__ __launch_bounds__(256) void mean_final(
    const float* __restrict__ sum, float* __restrict__ mean) {
  const int i = blockIdx.x * 256 + threadIdx.x;
  mean[i] = sum[i] * (1.0f / HW);
}

// ---------------------------------------------------------------- k/v small GEMM
__global__ __launch_bounds__(256) void kv_gemm(
    const float* __restrict__ l, const float* __restrict__ lmask,
    const float* __restrict__ wk, const float* __restrict__ bk,
    const float* __restrict__ wv, const float* __restrict__ bv,
    float* __restrict__ Kout, float* __restrict__ Vout) {
  const int b = blockIdx.z;
  const int o0 = blockIdx.x * 64;
  const float* w = blockIdx.y ? wv : wk;
  const float* bb = blockIdx.y ? bv : bk;
  float* out = blockIdx.y ? Vout : Kout;

  __shared__ float wl[64 * 129];
  __shared__ float ll[32 * 129];
  const int tid = threadIdx.x;
  const int o = tid & 63, ng = tid >> 6;  // each thread: 1 o x 8 n
  float acc[8];
#pragma unroll
  for (int j = 0; j < 8; ++j) acc[j] = 0.f;

  for (int kc = 0; kc < LIN; kc += 128) {
    for (int e = tid; e < 64 * 128; e += 256)
      wl[(e >> 7) * 129 + (e & 127)] =
          w[(size_t)(o0 + (e >> 7)) * LIN + kc + (e & 127)];
    for (int e = tid; e < 32 * 128; e += 256)
      ll[(e >> 7) * 129 + (e & 127)] =
          l[(size_t)b * NL * LIN + (size_t)(e >> 7) * LIN + kc + (e & 127)];
    __syncthreads();
    for (int k = 0; k < 128; ++k) {
      const float wv_ = wl[o * 129 + k];
#pragma unroll
      for (int j = 0; j < 8; ++j) acc[j] += wv_ * ll[(ng * 8 + j) * 129 + k];
    }
    __syncthreads();
  }
  const float bval = bb[o0 + o];
#pragma unroll
  for (int j = 0; j < 8; ++j) {
    const int n = ng * 8 + j;
    out[((size_t)b * DIM + o0 + o) * NL + n] =
        (acc[j] + bval) * lmask[b * NL + n];
  }
}

// ---------------------------------------------------------------- attention
// Per (b,h,m): scores over 32 keys (dk=128), softmax, weighted sum of v.
// Output written as f16 (centered later). Fused: column sums (f32) for
// amean via wave-reduce + direct atomicAdd into asum[b*DIM+col].
__global__ __launch_bounds__(256) void attn_kernel(
    const f16* __restrict__ Q, const float* __restrict__ qmean,
    const float* __restrict__ qrinv, const float* __restrict__ Kk,
    const float* __restrict__ Vv, const float* __restrict__ lmask,
    f16* __restrict__ Out, float* __restrict__ asum) {
  const int b = blockIdx.z, h = blockIdx.y;
  __shared__ float ks[128 * NL], vs[128 * NL], qm[128], qr[128], bs[NL];
  const int tid = threadIdx.x;
  const float* kbase = Kk + ((size_t)b * DIM + h * 128) * NL;
  const float* vbase = Vv + ((size_t)b * DIM + h * 128) * NL;
  for (int i = tid; i < 128 * NL; i += 256) {
    ks[i] = kbase[i];
    vs[i] = vbase[i];
  }
  if (tid < 128) {
    qm[tid] = qmean[b * DIM + h * 128 + tid];
    qr[tid] = qrinv[b * DIM + h * 128 + tid];
  }
  if (tid < NL) bs[tid] = (lmask[b * NL + tid] - 1.0f) * 10000.0f;
  __syncthreads();

  const int mloc = blockIdx.x * 256 + tid;
  const bool valid = mloc < HW;
  const int mc = valid ? mloc : HW - 1;
  const size_t m = (size_t)b * HW + mc;
  const f16* qrow = Q + m * DIM + h * 128;

  float sc[32];
#pragma unroll
  for (int n = 0; n < 32; ++n) sc[n] = 0.f;

  for (int d8 = 0; d8 < 16; ++d8) {
    const f16x8 qv = *(const f16x8*)(qrow + d8 * 8);
#pragma unroll
    for (int j = 0; j < 8; ++j) {
      const int d = d8 * 8 + j;
      const float qd = ((float)qv[j] - qm[d]) * qr[d];
      const float4* kr = (const float4*)&ks[d * 32];
#pragma unroll
      for (int n4 = 0; n4 < 8; ++n4) {
        const float4 kk = kr[n4];
        sc[n4 * 4 + 0] += qd * kk.x;
        sc[n4 * 4 + 1] += qd * kk.y;
        sc[n4 * 4 + 2] += qd * kk.z;
        sc[n4 * 4 + 3] += qd * kk.w;
      }
    }
  }
  float mx = -1e30f;
#pragma unroll
  for (int n = 0; n < 32; ++n) {
    sc[n] = sc[n] * 0.03125f + bs[n];  // * KC^-0.5 then masked bias
    mx = fmaxf(mx, sc[n]);
  }
  float sum = 0.f;
#pragma unroll
  for (int n = 0; n < 32; ++n) {
    sc[n] = __expf(sc[n] - mx);
    sum += sc[n];
  }
  const float rs = 1.0f / sum;

  f16* orow = Out + m * DIM + h * 128;
  float* abase = asum + (size_t)b * DIM + h * 128;
  for (int dv8 = 0; dv8 < 16; ++dv8) {
    float ov[8];
#pragma unroll
    for (int j = 0; j < 8; ++j) {
      const float4* vr = (const float4*)&vs[(dv8 * 8 + j) * 32];
      float a = 0.f;
#pragma unroll
      for (int n4 = 0; n4 < 8; ++n4) {
        const float4 vv = vr[n4];
        a += sc[n4 * 4 + 0] * vv.x + sc[n4 * 4 + 1] * vv.y +
             sc[n4 * 4 + 2] * vv.z + sc[n4 * 4 + 3] * vv.w;
      }
      ov[j] = a * rs;
    }
    if (valid) {
      f16x8 o = {(f16)ov[0], (f16)ov[1], (f16)ov[2], (f16)ov[3],
                 (f16)ov[4], (f16)ov[5], (f16)ov[6], (f16)ov[7]};
      *(f16x8*)(orow + dv8 * 8) = o;
    }
#pragma unroll
    for (int j = 0; j < 8; ++j) {
      float v = valid ? ov[j] : 0.f;
      v += __shfl_down(v, 32);
      v += __shfl_down(v, 16);
      v += __shfl_down(v, 8);
      v += __shfl_down(v, 4);
      v += __shfl_down(v, 2);
      v += __shfl_down(v, 1);
      if ((tid & 63) == 0) atomicAdd(&abase[dv8 * 8 + j], v);
    }
  }
}

// ---------------------------------------------------------------- center (attn f16 - colmean) -> f16
__global__ void center_kernel(const f16* __restrict__ X,
                              const float* __restrict__ mean,
                              f16* __restrict__ out, int nchunks) {
  const int i = blockIdx.x * 256 + threadIdx.x;
  if (i >= nchunks) return;
  const size_t e = (size_t)i * 8;
  const int mrow = (int)(e >> 10);
  const int o = (int)(e & 1023);
  const int b = mrow / HW;
  const f16x8 v = *((const f16x8*)X + i);
  const float* mn = mean + b * DIM + o;
  f16x8 r;
#pragma unroll
  for (int j = 0; j < 8; ++j) r[j] = (f16)((float)v[j] - mn[j]);
  *((f16x8*)out + i) = r;
}

// ---------------------------------------------------------------- fuse: mm = vis * inorm(lang_pre)
__global__ void fuse_kernel(const f16* __restrict__ vis,
                            const f16* __restrict__ lang,
                            const float* __restrict__ mean,
                            const float* __restrict__ rinv,
                            f16* __restrict__ out, int nchunks) {
  const int i = blockIdx.x * 256 + threadIdx.x;
  if (i >= nchunks) return;
  const size_t e = (size_t)i * 8;
  const int mrow = (int)(e >> 10);
  const int o = (int)(e & 1023);
  const int b = mrow / HW;
  const f16x8 v = *((const f16x8*)vis + i);
  const f16x8 lv = *((const f16x8*)lang + i);
  const float* mn = mean + b * DIM + o;
  const float* ri = rinv + b * DIM + o;
  f16x8 r;
#pragma unroll
  for (int j = 0; j < 8; ++j)
    r[j] = (f16)((float)v[j] * (((float)lv[j] - mn[j]) * ri[j]));
  *((f16x8*)out + i) = r;
}

// ---------------------------------------------------------------- launch
extern "C" void kernel_launch(void* const* d_in, const int* in_sizes, int n_in,
                              void* d_out, int out_size, void* d_ws,
                              size_t ws_size, hipStream_t stream) {
  const float* x     = (const float*)d_in[0];
  const float* l     = (const float*)d_in[1];
  const float* lmask = (const float*)d_in[2];
  const float* vis_w = (const float*)d_in[3];
  const float* vis_b = (const float*)d_in[4];
  const float* fq_w  = (const float*)d_in[5];
  const float* fq_b  = (const float*)d_in[6];
  const float* fk_w  = (const float*)d_in[7];
  const float* fk_b  = (const float*)d_in[8];
  const float* fv_w  = (const float*)d_in[9];
  const float* fv_b  = (const float*)d_in[10];
  const float* W_w   = (const float*)d_in[11];
  const float* W_b   = (const float*)d_in[12];
  const float* pm_w  = (const float*)d_in[13];
  const float* pm_b  = (const float*)d_in[14];

  char* ws = (char*)d_ws;
  const size_t SB = (size_t)MTOT * DIM * 2;  // one f16 [M,1024] buffer
  f16* Ah  = (f16*)(ws);              // x_f16 -> centered attn -> mm
  f16* Bh  = (f16*)(ws + SB);         // vis
  f16* Ch  = (f16*)(ws + 2 * SB);     // q (f16)
  f16* O16 = (f16*)(ws + 3 * SB);     // attn out (f16)
  f16* E16 = (f16*)(ws + 4 * SB);     // lang_pre (f16)
  char* wsp = ws + 5 * SB;
  f16* vis_wh = (f16*)(wsp);
  f16* fq_wh  = (f16*)(wsp + (1 << 21));
  f16* W_wh   = (f16*)(wsp + 2 * (1 << 21));
  f16* pm_wh  = (f16*)(wsp + 3 * (1 << 21));
  float* Kout = (float*)(wsp + 4 * (1 << 21));
  float* Vout = (float*)(wsp + 4 * (1 << 21) + (1 << 20));
  float* st   = (float*)(wsp + 4 * (1 << 21) + 2 * (1 << 20));
  float* qmean = st;
  float* qrinv = st + 8192;
  float* amean = st + 16384;
  float* lmean = st + 24576;
  float* lrinv = st + 32768;
  // stats accumulators (zeroed each launch): qsum qsq asum lsum lsq
  float* stats = (float*)(wsp + 4 * (1 << 21) + 3 * (1 << 20));
  float* qsum = stats;
  float* qsq  = stats + 8192;
  float* asum = stats + 16384;
  float* lsum = stats + 24576;
  float* lsq  = stats + 32768;

  const int NCH_BIG = MTOT * DIM / 8;  // 5,607,424 chunks of 8
  const int NCH_W = DIM * DIM / 8;     // 131,072

  hipMemsetAsync(stats, 0, 5 * 8192 * sizeof(float), stream);

  cvt_f32_f16<<<(NCH_BIG + 255) / 256, 256, 0, stream>>>(x, Ah, NCH_BIG);
  cvt_f32_f16<<<(NCH_W + 255) / 256, 256, 0, stream>>>(vis_w, vis_wh, NCH_W);
  cvt_f32_f16<<<(NCH_W + 255) / 256, 256, 0, stream>>>(fq_w, fq_wh, NCH_W);
  cvt_f32_f16<<<(NCH_W + 255) / 256, 256, 0, stream>>>(W_w, W_wh, NCH_W);
  cvt_f32_f16<<<(NCH_W + 255) / 256, 256, 0, stream>>>(pm_w, pm_wh, NCH_W);

  kv_gemm<<<dim3(16, 2, 8), 256, 0, stream>>>(l, lmask, fk_w, fk_b, fv_w, fv_b,
                                              Kout, Vout);

  // vis + q fused; q column stats fused into epilogue.
  gemm256<0, 1, 1><<<8 * MT256, 512, 0, stream>>>(
      Ah, vis_wh, vis_b, Bh, fq_wh, fq_b, Ch, qsum, qsq, MTOT);
  mean_rinv_final<<<32, 256, 0, stream>>>(qsum, qsq, qmean, qrinv);

  // attn (f16 out) with fused column sums for amean.
  attn_kernel<<<dim3((HW + 255) / 256, 8, 8), 256, 0, stream>>>(
      Ch, qmean, qrinv, Kout, Vout, lmask, O16, asum);
  mean_final<<<32, 256, 0, stream>>>(asum, amean);
  center_kernel<<<(NCH_BIG + 255) / 256, 256, 0, stream>>>(O16, amean, Ah,
                                                           NCH_BIG);

  // lang_pre (f16 out) with fused lang column stats.
  gemm256<1, -1, 2><<<4 * MT256, 512, 0, stream>>>(
      Ah, W_wh, W_b, E16, nullptr, nullptr, nullptr, lsum, lsq, MTOT);
  mean_rinv_final<<<32, 256, 0, stream>>>(lsum, lsq, lmean, lrinv);
  fuse_kernel<<<(NCH_BIG + 255) / 256, 256, 0, stream>>>(Bh, E16, lmean, lrinv,
                                                         Ah, NCH_BIG);

  gemm256<3, -1, 0><<<4 * MT256, 512, 0, stream>>>(
      Ah, pm_wh, pm_b, d_out, nullptr, nullptr, nullptr, nullptr, nullptr,
      MTOT);  // output
}